// Round 1
// baseline (628.167 us; speedup 1.0000x reference)
//
#include <hip/hip_runtime.h>

typedef short bf16x8 __attribute__((ext_vector_type(8)));
typedef float f32x4 __attribute__((ext_vector_type(4)));
typedef unsigned short u16;

#define S_LEN 2048
#define DM 1024
#define NH 16
#define DK 64
#define BHD ((size_t)S_LEN * DK) /* elements per (b,h) head = 131072 */

static __device__ __forceinline__ u16 f2bf(float f) {
  union { float f; unsigned u; } x; x.f = f;
  unsigned r = x.u + 0x7FFFu + ((x.u >> 16) & 1u);
  return (u16)(r >> 16);
}

// ---------------- QKV projection: Y = X @ W^T + b  (fp32 in, bf16 head-split out) ----------
__global__ __launch_bounds__(256) void proj_kernel(
    const float* __restrict__ xq, const float* __restrict__ xk, const float* __restrict__ xv,
    const float* __restrict__ Wq, const float* __restrict__ Wk, const float* __restrict__ Wv,
    const float* __restrict__ bq, const float* __restrict__ bk, const float* __restrict__ bv,
    u16* __restrict__ qws, u16* __restrict__ kws, u16* __restrict__ vws)
{
  __shared__ u16 Al[128 * 40];
  __shared__ u16 Bl[128 * 40];
  const int z = blockIdx.z;
  const float* X    = (z == 0) ? xq : ((z == 1) ? xk : xv);
  const float* W    = (z == 0) ? Wq : ((z == 1) ? Wk : Wv);
  const float* bias = (z == 0) ? bq : ((z == 1) ? bk : bv);

  const int t = threadIdx.x;
  const int l = t & 63, w = t >> 6;
  const int lr = l & 15, lg = l >> 4;
  const int wm = w >> 1, wn = w & 1;
  const int m0 = blockIdx.x * 128, n0 = blockIdx.y * 128;

  f32x4 acc[4][4] = {};
  for (int k0 = 0; k0 < DM; k0 += 32) {
#pragma unroll
    for (int j = 0; j < 4; ++j) {
      int i = t + 256 * j;
      int r = i >> 3, c = (i & 7) * 4;
      float4 va = *(const float4*)(X + (size_t)(m0 + r) * DM + k0 + c);
      float4 vb = *(const float4*)(W + (size_t)(n0 + r) * DM + k0 + c);
      ushort4 ha, hb;
      ha.x = f2bf(va.x); ha.y = f2bf(va.y); ha.z = f2bf(va.z); ha.w = f2bf(va.w);
      hb.x = f2bf(vb.x); hb.y = f2bf(vb.y); hb.z = f2bf(vb.z); hb.w = f2bf(vb.w);
      *(ushort4*)(Al + r * 40 + c) = ha;
      *(ushort4*)(Bl + r * 40 + c) = hb;
    }
    __syncthreads();
    bf16x8 a[4], b[4];
#pragma unroll
    for (int mi = 0; mi < 4; ++mi)
      a[mi] = *(const bf16x8*)(Al + (wm * 64 + mi * 16 + lr) * 40 + lg * 8);
#pragma unroll
    for (int ni = 0; ni < 4; ++ni)
      b[ni] = *(const bf16x8*)(Bl + (wn * 64 + ni * 16 + lr) * 40 + lg * 8);
#pragma unroll
    for (int mi = 0; mi < 4; ++mi)
#pragma unroll
      for (int ni = 0; ni < 4; ++ni)
        acc[mi][ni] = __builtin_amdgcn_mfma_f32_16x16x32_bf16(a[mi], b[ni], acc[mi][ni], 0, 0, 0);
    __syncthreads();
  }

#pragma unroll
  for (int mi = 0; mi < 4; ++mi) {
#pragma unroll
    for (int ni = 0; ni < 4; ++ni) {
#pragma unroll
      for (int r = 0; r < 4; ++r) {
        int m = m0 + wm * 64 + mi * 16 + lg * 4 + r;
        int n = n0 + wn * 64 + ni * 16 + lr;
        float y = acc[mi][ni][r] + bias[n];
        u16 h = f2bf(y);
        int b_ = m >> 11, s = m & 2047, hh = n >> 6, d = n & 63;
        size_t head = (size_t)(b_ * NH + hh);
        if (z == 0)      qws[head * BHD + (size_t)s * DK + d] = h;
        else if (z == 1) kws[head * BHD + (size_t)s * DK + d] = h;
        else             vws[head * BHD + (size_t)d * S_LEN + s] = h;  // V stored transposed
      }
    }
  }
}

// ---------------- flash attention: per (b,h), 64 q-rows per block (16 per wave) -----------
__global__ __launch_bounds__(256) void attn_kernel(
    const u16* __restrict__ qh, const u16* __restrict__ kh,
    const u16* __restrict__ vt, u16* __restrict__ aout)
{
  __shared__ u16 P[4][16 * 40];  // per-wave P tile (16 q x 32 k), padded stride 40
  const int t = threadIdx.x;
  const int l = t & 63, w = t >> 6;
  const int lr = l & 15, lg = l >> 4;
  const int bh = blockIdx.y;
  const int qb = blockIdx.x * 64 + w * 16;
  const u16* qp = qh + (size_t)bh * BHD;
  const u16* kp = kh + (size_t)bh * BHD;
  const u16* vp = vt + (size_t)bh * BHD;
  u16* Pw = &P[w][0];

  bf16x8 qf[2];
#pragma unroll
  for (int c = 0; c < 2; ++c)
    qf[c] = *(const bf16x8*)(qp + (size_t)(qb + lr) * DK + c * 32 + lg * 8);

  f32x4 acc[4] = {};
  float mr[4], ls[4];
#pragma unroll
  for (int r = 0; r < 4; ++r) { mr[r] = -1e30f; ls[r] = 0.0f; }

  for (int kv = 0; kv < S_LEN; kv += 32) {
    f32x4 sc[2] = {};
#pragma unroll
    for (int ct = 0; ct < 2; ++ct)
#pragma unroll
      for (int c = 0; c < 2; ++c) {
        bf16x8 kf = *(const bf16x8*)(kp + (size_t)(kv + ct * 16 + lr) * DK + c * 32 + lg * 8);
        sc[ct] = __builtin_amdgcn_mfma_f32_16x16x32_bf16(qf[c], kf, sc[ct], 0, 0, 0);
      }
#pragma unroll
    for (int r = 0; r < 4; ++r) {
      float s0 = sc[0][r] * 0.125f, s1 = sc[1][r] * 0.125f;
      float pm = fmaxf(s0, s1);
      pm = fmaxf(pm, __shfl_xor(pm, 1));
      pm = fmaxf(pm, __shfl_xor(pm, 2));
      pm = fmaxf(pm, __shfl_xor(pm, 4));
      pm = fmaxf(pm, __shfl_xor(pm, 8));
      float mn = fmaxf(mr[r], pm);
      float al = __expf(mr[r] - mn);
      float p0 = __expf(s0 - mn), p1 = __expf(s1 - mn);
      float ps = p0 + p1;
      ps += __shfl_xor(ps, 1);
      ps += __shfl_xor(ps, 2);
      ps += __shfl_xor(ps, 4);
      ps += __shfl_xor(ps, 8);
      ls[r] = ls[r] * al + ps;
      mr[r] = mn;
#pragma unroll
      for (int ni = 0; ni < 4; ++ni) acc[ni][r] *= al;
      Pw[(lg * 4 + r) * 40 + lr]      = f2bf(p0);
      Pw[(lg * 4 + r) * 40 + 16 + lr] = f2bf(p1);
    }
    asm volatile("s_waitcnt lgkmcnt(0)" ::: "memory");  // wave-local P writes visible
    bf16x8 pf = *(const bf16x8*)(Pw + lr * 40 + lg * 8);
#pragma unroll
    for (int ni = 0; ni < 4; ++ni) {
      bf16x8 vf = *(const bf16x8*)(vp + (size_t)(ni * 16 + lr) * S_LEN + kv + lg * 8);
      acc[ni] = __builtin_amdgcn_mfma_f32_16x16x32_bf16(pf, vf, acc[ni], 0, 0, 0);
    }
    asm volatile("" ::: "memory");  // keep next-iter P writes after this iter's read
  }

  const int b_ = bh >> 4, hh = bh & 15;
#pragma unroll
  for (int r = 0; r < 4; ++r) {
    float inv = 1.0f / ls[r];
    int s = qb + lg * 4 + r;
#pragma unroll
    for (int ni = 0; ni < 4; ++ni)
      aout[((size_t)(b_ * S_LEN + s)) * DM + hh * DK + ni * 16 + lr] = f2bf(acc[ni][r] * inv);
  }
}

// ---------------- output projection: out = A(bf16) @ Wo^T + bo  (fp32 out) ----------------
__global__ __launch_bounds__(256) void oproj_kernel(
    const u16* __restrict__ ain, const float* __restrict__ Wo,
    const float* __restrict__ bo, float* __restrict__ out)
{
  __shared__ u16 Al[128 * 40];
  __shared__ u16 Bl[128 * 40];
  const int t = threadIdx.x;
  const int l = t & 63, w = t >> 6;
  const int lr = l & 15, lg = l >> 4;
  const int wm = w >> 1, wn = w & 1;
  const int m0 = blockIdx.x * 128, n0 = blockIdx.y * 128;

  f32x4 acc[4][4] = {};
  for (int k0 = 0; k0 < DM; k0 += 32) {
#pragma unroll
    for (int j = 0; j < 2; ++j) {
      int i = t + 256 * j;
      int r = i >> 2, c8 = (i & 3) * 8;
      uint4 v = *(const uint4*)(ain + (size_t)(m0 + r) * DM + k0 + c8);
      *(uint4*)(Al + r * 40 + c8) = v;
    }
#pragma unroll
    for (int j = 0; j < 4; ++j) {
      int i = t + 256 * j;
      int r = i >> 3, c = (i & 7) * 4;
      float4 vb = *(const float4*)(Wo + (size_t)(n0 + r) * DM + k0 + c);
      ushort4 hb;
      hb.x = f2bf(vb.x); hb.y = f2bf(vb.y); hb.z = f2bf(vb.z); hb.w = f2bf(vb.w);
      *(ushort4*)(Bl + r * 40 + c) = hb;
    }
    __syncthreads();
    bf16x8 a[4], b[4];
#pragma unroll
    for (int mi = 0; mi < 4; ++mi)
      a[mi] = *(const bf16x8*)(Al + (wm * 64 + mi * 16 + lr) * 40 + lg * 8);
#pragma unroll
    for (int ni = 0; ni < 4; ++ni)
      b[ni] = *(const bf16x8*)(Bl + (wn * 64 + ni * 16 + lr) * 40 + lg * 8);
#pragma unroll
    for (int mi = 0; mi < 4; ++mi)
#pragma unroll
      for (int ni = 0; ni < 4; ++ni)
        acc[mi][ni] = __builtin_amdgcn_mfma_f32_16x16x32_bf16(a[mi], b[ni], acc[mi][ni], 0, 0, 0);
    __syncthreads();
  }

#pragma unroll
  for (int mi = 0; mi < 4; ++mi) {
#pragma unroll
    for (int ni = 0; ni < 4; ++ni) {
#pragma unroll
      for (int r = 0; r < 4; ++r) {
        int m = m0 + wm * 64 + mi * 16 + lg * 4 + r;
        int n = n0 + wn * 64 + ni * 16 + lr;
        out[(size_t)m * DM + n] = acc[mi][ni][r] + bo[n];
      }
    }
  }
}

extern "C" void kernel_launch(void* const* d_in, const int* in_sizes, int n_in,
                              void* d_out, int out_size, void* d_ws, size_t ws_size,
                              hipStream_t stream) {
  (void)in_sizes; (void)n_in; (void)out_size; (void)ws_size;
  const float* q  = (const float*)d_in[0];
  const float* k  = (const float*)d_in[1];
  const float* v  = (const float*)d_in[2];
  const float* Wq = (const float*)d_in[3];
  const float* bq = (const float*)d_in[4];
  const float* Wk = (const float*)d_in[5];
  const float* bk = (const float*)d_in[6];
  const float* Wv = (const float*)d_in[7];
  const float* bv = (const float*)d_in[8];
  const float* Wo = (const float*)d_in[9];
  const float* bo = (const float*)d_in[10];
  float* out = (float*)d_out;

  // workspace: q | k | vT | attn_out, each 8192*1024 bf16 = 16 MB (64 MB total)
  u16* qws = (u16*)d_ws;
  u16* kws = qws + (size_t)8192 * 1024;
  u16* vws = kws + (size_t)8192 * 1024;
  u16* aws = vws + (size_t)8192 * 1024;

  dim3 g1(64, 8, 3);
  proj_kernel<<<g1, dim3(256), 0, stream>>>(q, k, v, Wq, Wk, Wv, bq, bk, bv, qws, kws, vws);
  dim3 g2(32, 64);
  attn_kernel<<<g2, dim3(256), 0, stream>>>(qws, kws, vws, aws);
  dim3 g3(64, 8);
  oproj_kernel<<<g3, dim3(256), 0, stream>>>(aws, Wo, bo, out);
}